// Round 3
// baseline (794.754 us; speedup 1.0000x reference)
//
#include <hip/hip_runtime.h>

#define NN   3072
#define EE   98304
#define CUMC 36
#define HIDC 64
#define OUTC 5

// R is [N, N, 9] floats. Row length 27648 floats = 27 chunks of 1024 floats.
// One "chunk" = 1024 contiguous floats = 256 lanes x float4, never straddles a row.
#define NCH   82944u   // total chunks = NN*NN*9/1024
#define CPR   27u      // chunks per i-row
#define HELP  3456u    // helper blocks appended to each of the 4 sliced kernels
#define BUD   6u       // chunks per helper block (24 KB of R per block)

// 4 equal, non-overlapping slices (HELP*BUD = 20736 chunks = 84.9 MB each)
#define SL_H1  0u
#define SL_H2  20736u
#define SL_AG  41472u
#define SL_HD  62208u   // 62208 + 20736 = 82944 = NCH, complete cover

// native clang vector type: __builtin_nontemporal_store requires it
typedef float f32x4 __attribute__((ext_vector_type(4)));

__device__ __forceinline__ float tanh_fast(float x) {
    // tanh(x) = 1 - 2/(exp(2x)+1); safe at +/-inf (no inf/inf).
    float t = __expf(2.0f * x);
    return 1.0f - 2.0f * __builtin_amdgcn_rcpf(t + 1.0f);
}

// ---- A = x @ Ws[0:3] + b_sheaf (bias folded in), B = x @ Ws[3:6] ----
__global__ __launch_bounds__(256) void ab_kernel(const float* __restrict__ x,
                                                 const float* __restrict__ Ws,
                                                 const float* __restrict__ bs,
                                                 float* __restrict__ Aa,
                                                 float* __restrict__ Bb) {
    int id = blockIdx.x * 256 + threadIdx.x;
    if (id >= NN * 9) return;
    int n = id / 9;
    int c = id - n * 9;
    float x0 = x[n * 3 + 0], x1 = x[n * 3 + 1], x2 = x[n * 3 + 2];
    Aa[id] = x0 * Ws[0 * 9 + c] + x1 * Ws[1 * 9 + c] + x2 * Ws[2 * 9 + c] + bs[c];
    Bb[id] = x0 * Ws[3 * 9 + c] + x1 * Ws[4 * 9 + c] + x2 * Ws[5 * 9 + c];
}

// ---- write one 1024-float chunk of R: R[i,j,c] = tanh(Aa'[i,c] + Bb[j,c]) ----
__device__ __forceinline__ void r_chunk(unsigned ch, unsigned lane,
                                        const float* __restrict__ Aa,
                                        const float* __restrict__ Bb,
                                        float* __restrict__ R) {
    unsigned i  = ch / CPR;                              // chunk-uniform row
    unsigned rp = (ch - i * CPR) * 1024u + lane * 4u;    // 0..27647
    unsigned j  = rp / 9u;
    unsigned c  = rp - j * 9u;
    const float* Ar = Aa + i * 9u;
    f32x4 v;
#pragma unroll
    for (int u = 0; u < 4; ++u) {
        v[u] = tanh_fast(Ar[c] + Bb[j * 9u + c]);
        if (u < 3 && ++c == 9u) { c = 0u; ++j; }         // never walks past j=3071
    }
    // non-temporal: 340 MB stream nothing ever reads back on-device
    __builtin_nontemporal_store(v, reinterpret_cast<f32x4*>(R) + ((size_t)ch * 256u + lane));
}

__device__ __forceinline__ void r_slice(unsigned base, unsigned lane,
                                        const float* __restrict__ Aa,
                                        const float* __restrict__ Bb,
                                        float* __restrict__ R) {
#pragma unroll
    for (unsigned u = 0; u < BUD; ++u)
        r_chunk(base + u, lane, Aa, Bb, R);
}

// ================= edge-scatter chain (no CSR), each with R-helper blocks ====

// h1[t, k*3+d] += K[k,e]*x[s,d]; deg count  (+ R slice)
__global__ __launch_bounds__(256) void hop1s(const int* __restrict__ src,
                                             const int* __restrict__ tgt,
                                             const float* __restrict__ K,
                                             const float* __restrict__ x,
                                             float* __restrict__ h1,
                                             int* __restrict__ cnt,
                                             const float* __restrict__ Aa,
                                             const float* __restrict__ Bb,
                                             float* __restrict__ R) {
    unsigned b = blockIdx.x, tid = threadIdx.x;
    if (b < EE / 256u) {                       // 384 main blocks, exact cover
        int e = b * 256u + tid;
        int t = tgt[e], s = src[e];
        float x0 = x[s * 3 + 0], x1 = x[s * 3 + 1], x2 = x[s * 3 + 2];
        float K0 = K[e], K1 = K[EE + e], K2 = K[2 * EE + e];
        atomicAdd(&cnt[t], 1);
        float* h = h1 + t * 9;
        unsafeAtomicAdd(h + 0, K0 * x0); unsafeAtomicAdd(h + 1, K0 * x1); unsafeAtomicAdd(h + 2, K0 * x2);
        unsafeAtomicAdd(h + 3, K1 * x0); unsafeAtomicAdd(h + 4, K1 * x1); unsafeAtomicAdd(h + 5, K1 * x2);
        unsafeAtomicAdd(h + 6, K2 * x0); unsafeAtomicAdd(h + 7, K2 * x1); unsafeAtomicAdd(h + 8, K2 * x2);
        return;
    }
    r_slice(SL_H1 + (b - EE / 256u) * BUD, tid, Aa, Bb, R);
}

// h2[t, k*9+d] += K[k,e]*h1[s,d]; agg[t, 0:9] += h1[s, 0:9]  (+ R slice)
__global__ __launch_bounds__(256) void hop2s(const int* __restrict__ src,
                                             const int* __restrict__ tgt,
                                             const float* __restrict__ K,
                                             const float* __restrict__ h1,
                                             float* __restrict__ h2,
                                             float* __restrict__ agg,
                                             const float* __restrict__ Aa,
                                             const float* __restrict__ Bb,
                                             float* __restrict__ R) {
    unsigned b = blockIdx.x, tid = threadIdx.x;
    if (b < EE / 256u) {
        int e = b * 256u + tid;
        int t = tgt[e], s = src[e];
        float K0 = K[e], K1 = K[EE + e], K2 = K[2 * EE + e];
        const float* hp = h1 + s * 9;
        float* H  = h2  + t * 27;
        float* ag = agg + t * 36;
#pragma unroll
        for (int d = 0; d < 9; ++d) {
            float hd = hp[d];
            unsafeAtomicAdd(H + d,      K0 * hd);
            unsafeAtomicAdd(H + 9 + d,  K1 * hd);
            unsafeAtomicAdd(H + 18 + d, K2 * hd);
            unsafeAtomicAdd(ag + d, hd);
        }
        return;
    }
    r_slice(SL_H2 + (b - EE / 256u) * BUD, tid, Aa, Bb, R);
}

// agg[t, 9:36] += h2[s, 0:27]  (+ R slice)
__global__ __launch_bounds__(256) void aggs(const int* __restrict__ src,
                                            const int* __restrict__ tgt,
                                            const float* __restrict__ h2,
                                            float* __restrict__ agg,
                                            const float* __restrict__ Aa,
                                            const float* __restrict__ Bb,
                                            float* __restrict__ R) {
    unsigned b = blockIdx.x, tid = threadIdx.x;
    if (b < EE / 256u) {
        int e = b * 256u + tid;
        int t = tgt[e], s = src[e];
        const float* hp = h2 + s * 27;
        float* ag = agg + t * 36 + 9;
#pragma unroll
        for (int d = 0; d < 27; ++d)
            unsafeAtomicAdd(ag + d, hp[d]);
        return;
    }
    r_slice(SL_AG + (b - EE / 256u) * BUD, tid, Aa, Bb, R);
}

// fused mean + conv + MLP head, 4 nodes per 256-thread block  (+ R slice)
__global__ __launch_bounds__(256) void head_help(const int* __restrict__ cnt,
                                                 const float* __restrict__ agg,
                                                 const float* __restrict__ Wc,
                                                 const float* __restrict__ bc,
                                                 const float* __restrict__ W1,
                                                 const float* __restrict__ b1,
                                                 const float* __restrict__ W2,
                                                 const float* __restrict__ b2,
                                                 float* __restrict__ out,
                                                 const float* __restrict__ Aa,
                                                 const float* __restrict__ Bb,
                                                 float* __restrict__ R) {
    unsigned b = blockIdx.x, tid = threadIdx.x;
    if (b < NN / 4u) {                        // 768 main blocks, 4 nodes each
        __shared__ float aL[4][CUMC];
        __shared__ float xL[4][CUMC];
        __shared__ float hL[4][HIDC];
        int sub = tid >> 6, lane = tid & 63;
        int n = b * 4 + sub;
        int dg = cnt[n];
        float inv = 1.0f / (float)(dg > 1 ? dg : 1);
        if (lane < CUMC) aL[sub][lane] = agg[n * CUMC + lane] * inv;
        __syncthreads();
        if (lane < CUMC) {
            float acc = bc[lane];
#pragma unroll
            for (int k = 0; k < CUMC; ++k) acc += aL[sub][k] * Wc[k * CUMC + lane];
            xL[sub][lane] = acc > 0.0f ? acc : 0.0f;
        }
        __syncthreads();
        {
            float acc = b1[lane];
#pragma unroll
            for (int k = 0; k < CUMC; ++k) acc += xL[sub][k] * W1[k * HIDC + lane];
            hL[sub][lane] = acc > 0.0f ? acc : 0.0f;
        }
        __syncthreads();
        if (lane < OUTC) {
            float acc = b2[lane];
#pragma unroll
            for (int k = 0; k < HIDC; ++k) acc += hL[sub][k] * W2[k * OUTC + lane];
            out[n * OUTC + lane] = acc;
        }
        return;
    }
    r_slice(SL_HD + (b - NN / 4u) * BUD, tid, Aa, Bb, R);
}

extern "C" void kernel_launch(void* const* d_in, const int* in_sizes, int n_in,
                              void* d_out, int out_size, void* d_ws, size_t ws_size,
                              hipStream_t stream) {
    const float* x   = (const float*)d_in[0];
    const int*   ei  = (const int*)  d_in[1];
    const float* Kv  = (const float*)d_in[2];
    const float* Ws  = (const float*)d_in[3];
    const float* bsh = (const float*)d_in[4];
    const float* Wc  = (const float*)d_in[5];
    const float* bc  = (const float*)d_in[6];
    const float* W1  = (const float*)d_in[7];
    const float* b1  = (const float*)d_in[8];
    const float* W2  = (const float*)d_in[9];
    const float* b2  = (const float*)d_in[10];

    const int* src = ei;
    const int* tgt = ei + EE;

    float* out  = (float*)d_out;                 // [N,5]
    float* Rout = out + NN * OUTC;               // [N,N,9], 16B-aligned

    // ---- workspace layout: zeroed region first (single memset) ----
    float* wsf = (float*)d_ws;
    float* h1  = wsf;                  // N*9
    float* h2  = h1 + NN * 9;          // N*27
    float* agg = h2 + NN * 27;         // N*36
    int*   cnt = (int*)(agg + NN * CUMC); // N
    float* Aa  = (float*)(cnt + NN);   // N*9  (bias folded in)
    float* Bb  = Aa + NN * 9;          // N*9

    // zero h1 | h2 | agg | cnt in one shot: N*(72 floats + 1 int) = 897 KB
    (void)hipMemsetAsync(h1, 0, (size_t)NN * (72 * sizeof(float) + sizeof(int)), stream);

    // tiny producer: A(+bias)/B rows (no helpers — Aa/Bb not ready yet)
    ab_kernel<<<(NN * 9) / 256, 256, 0, stream>>>(x, Ws, bsh, Aa, Bb);

    // edge-scatter chain, each overlapped with a static 84.9 MB slice of R
    hop1s<<<EE / 256 + HELP, 256, 0, stream>>>(src, tgt, Kv, x, h1, cnt, Aa, Bb, Rout);
    hop2s<<<EE / 256 + HELP, 256, 0, stream>>>(src, tgt, Kv, h1, h2, agg, Aa, Bb, Rout);
    aggs <<<EE / 256 + HELP, 256, 0, stream>>>(src, tgt, h2, agg, Aa, Bb, Rout);
    head_help<<<NN / 4 + HELP, 256, 0, stream>>>(cnt, agg, Wc, bc, W1, b1, W2, b2,
                                                 out, Aa, Bb, Rout);
}

// Round 4
// 495.677 us; speedup vs baseline: 1.6034x; 1.6034x over previous
//
#include <hip/hip_runtime.h>

#define NN   3072
#define EE   98304
#define CUMC 36
#define HIDC 64
#define OUTC 5

// R is [N, N, 9] floats. Row length 27648 floats = 27 chunks of 1024 floats.
// One "chunk" = 1024 contiguous floats = 256 lanes x float4, never straddles a row.
#define NCH   82944u   // total chunks = NN*NN*9/1024
#define CPR   27u      // chunks per i-row
#define BUD   6u       // chunks per 256-thread helper block (24 KB of R)

// helper-block counts and chunk-slice bases (complete, non-overlapping cover)
#define HELP_S  576u    // scan helpers: 1024-thread, 24 chunks each -> 13824
#define HELP2   2880u   // 256-thread helpers x BUD -> 17280 chunks each kernel
#define SL_SCAN 0u
#define SL_SCAT 13824u
#define SL_HOP1 31104u
#define SL_HOP2 48384u
#define SL_HEAD 65664u  // + 17280 = 82944 = NCH

// native clang vector type: __builtin_nontemporal_store requires it
typedef float f32x4 __attribute__((ext_vector_type(4)));

__device__ __forceinline__ float tanh_fast(float x) {
    // tanh(x) = 1 - 2/(exp(2x)+1); safe at +/-inf (no inf/inf).
    float t = __expf(2.0f * x);
    return 1.0f - 2.0f * __builtin_amdgcn_rcpf(t + 1.0f);
}

// ---- write one 1024-float chunk of R: R[i,j,c] = tanh(Aa'[i,c] + Bb[j,c]) ----
__device__ __forceinline__ void r_chunk(unsigned ch, unsigned lane,
                                        const float* __restrict__ Aa,
                                        const float* __restrict__ Bb,
                                        float* __restrict__ R) {
    unsigned i  = ch / CPR;                              // chunk-uniform row
    unsigned rp = (ch - i * CPR) * 1024u + lane * 4u;    // 0..27647
    unsigned j  = rp / 9u;
    unsigned c  = rp - j * 9u;
    const float* Ar = Aa + i * 9u;
    f32x4 v;
#pragma unroll
    for (int u = 0; u < 4; ++u) {
        v[u] = tanh_fast(Ar[c] + Bb[j * 9u + c]);
        if (u < 3 && ++c == 9u) { c = 0u; ++j; }         // never walks past j=3071
    }
    // non-temporal: 340 MB stream nothing ever reads back on-device
    __builtin_nontemporal_store(v, reinterpret_cast<f32x4*>(R) + ((size_t)ch * 256u + lane));
}

__device__ __forceinline__ void r_slice(unsigned base, unsigned lane,
                                        const float* __restrict__ Aa,
                                        const float* __restrict__ Bb,
                                        float* __restrict__ R) {
#pragma unroll
    for (unsigned u = 0; u < BUD; ++u)
        r_chunk(base + u, lane, Aa, Bb, R);
}

// ==== fused: A/B rows (blocks 0..107) + in-degree histogram (blocks 108..491) ====
__global__ __launch_bounds__(256) void abhist(const float* __restrict__ x,
                                              const float* __restrict__ Ws,
                                              const float* __restrict__ bs,
                                              const int* __restrict__ tgt,
                                              float* __restrict__ Aa,
                                              float* __restrict__ Bb,
                                              int* __restrict__ cnt) {
    unsigned b = blockIdx.x, tid = threadIdx.x;
    if (b < 108u) {                            // NN*9 = 27648 = 108*256 exactly
        int id = b * 256u + tid;
        int n = id / 9;
        int c = id - n * 9;
        float x0 = x[n * 3 + 0], x1 = x[n * 3 + 1], x2 = x[n * 3 + 2];
        Aa[id] = x0 * Ws[0 * 9 + c] + x1 * Ws[1 * 9 + c] + x2 * Ws[2 * 9 + c] + bs[c];
        Bb[id] = x0 * Ws[3 * 9 + c] + x1 * Ws[4 * 9 + c] + x2 * Ws[5 * 9 + c];
        return;
    }
    int e = (b - 108u) * 256u + tid;           // 384 blocks, exact cover of EE
    atomicAdd(&cnt[tgt[e]], 1);
}

// single-block exclusive scan of 3072 counts (+ 1024-thread R helpers)
__global__ __launch_bounds__(1024) void scan_help(const int* __restrict__ cnt,
                                                  int* __restrict__ rowptr,
                                                  int* __restrict__ cursor,
                                                  const float* __restrict__ Aa,
                                                  const float* __restrict__ Bb,
                                                  float* __restrict__ R) {
    unsigned b = blockIdx.x;
    int tid = threadIdx.x;
    if (b == 0) {
        __shared__ int sums[1024];
        int base = tid * 3;
        int c0 = cnt[base], c1 = cnt[base + 1], c2 = cnt[base + 2];
        sums[tid] = c0 + c1 + c2;
        __syncthreads();
        for (int off = 1; off < 1024; off <<= 1) {
            int add = (tid >= off) ? sums[tid - off] : 0;
            __syncthreads();
            sums[tid] += add;
            __syncthreads();
        }
        int excl = (tid == 0) ? 0 : sums[tid - 1];
        rowptr[base] = excl;               cursor[base] = excl;
        rowptr[base + 1] = excl + c0;      cursor[base + 1] = excl + c0;
        rowptr[base + 2] = excl + c0 + c1; cursor[base + 2] = excl + c0 + c1;
        if (tid == 1023) rowptr[NN] = sums[1023];
        return;
    }
    // HELP_S helper blocks x 1024 threads: 4 chunk-streams per block, 24 chunks total
    unsigned hb   = b - 1u;
    unsigned lane = (unsigned)tid & 255u;
    unsigned sub  = (unsigned)tid >> 8;
    unsigned base = SL_SCAN + hb * 24u + sub;
#pragma unroll
    for (unsigned u = 0; u < 6u; ++u)
        r_chunk(base + u * 4u, lane, Aa, Bb, R);
}

// edge placement into CSR (+ R slice)
__global__ __launch_bounds__(256) void scatter_help(const int* __restrict__ src,
                                                    const int* __restrict__ tgt,
                                                    int* __restrict__ cursor,
                                                    int* __restrict__ srcs,
                                                    int* __restrict__ eids,
                                                    const float* __restrict__ Aa,
                                                    const float* __restrict__ Bb,
                                                    float* __restrict__ R) {
    unsigned b = blockIdx.x, tid = threadIdx.x;
    if (b < EE / 256u) {
        int e = b * 256u + tid;
        int t = tgt[e];
        int pos = atomicAdd(&cursor[t], 1);
        srcs[pos] = src[e];
        eids[pos] = e;
        return;
    }
    r_slice(SL_SCAT + (b - EE / 256u) * BUD, tid, Aa, Bb, R);
}

// h1[t, k*3+d] = sum_e K[k,e] * x[src,d]  (+ R slice)
__global__ __launch_bounds__(256) void hop1_help(const int* __restrict__ rowptr,
                                                 const int* __restrict__ srcs,
                                                 const int* __restrict__ eids,
                                                 const float* __restrict__ K,
                                                 const float* __restrict__ x,
                                                 float* __restrict__ h1,
                                                 const float* __restrict__ Aa,
                                                 const float* __restrict__ Bb,
                                                 float* __restrict__ R) {
    unsigned b = blockIdx.x, tid = threadIdx.x;
    if (b < (NN * 9u) / 256u) {               // 108 main blocks, exact cover
        int id = b * 256u + tid;
        int t = id / 9;
        int c = id - t * 9;
        int k = c / 3, d = c - k * 3;
        int p0 = rowptr[t], p1 = rowptr[t + 1];
        const float* Kk = K + (size_t)k * EE;
        float acc = 0.0f;
        for (int p = p0; p < p1; ++p)
            acc += Kk[eids[p]] * x[srcs[p] * 3 + d];
        h1[id] = acc;
        return;
    }
    r_slice(SL_HOP1 + (b - (NN * 9u) / 256u) * BUD, tid, Aa, Bb, R);
}

// h2[t, k*9+d] = sum_e K[k,e] * h1[src,d]  (+ R slice)
__global__ __launch_bounds__(256) void hop2_help(const int* __restrict__ rowptr,
                                                 const int* __restrict__ srcs,
                                                 const int* __restrict__ eids,
                                                 const float* __restrict__ K,
                                                 const float* __restrict__ h1,
                                                 float* __restrict__ h2,
                                                 const float* __restrict__ Aa,
                                                 const float* __restrict__ Bb,
                                                 float* __restrict__ R) {
    unsigned b = blockIdx.x, tid = threadIdx.x;
    if (b < (NN * 27u) / 256u) {              // 324 main blocks, exact cover
        int id = b * 256u + tid;
        int t = id / 27;
        int c = id - t * 27;
        int k = c / 9, d = c - k * 9;
        int p0 = rowptr[t], p1 = rowptr[t + 1];
        const float* Kk = K + (size_t)k * EE;
        float acc = 0.0f;
        for (int p = p0; p < p1; ++p)
            acc += Kk[eids[p]] * h1[srcs[p] * 9 + d];
        h2[id] = acc;
        return;
    }
    r_slice(SL_HOP2 + (b - (NN * 27u) / 256u) * BUD, tid, Aa, Bb, R);
}

// fused mean-aggregate + conv + MLP head, 4 nodes per 256-thread block (+ R slice)
__global__ __launch_bounds__(256) void head_help(const int* __restrict__ rowptr,
                                                 const int* __restrict__ srcs,
                                                 const float* __restrict__ h1,
                                                 const float* __restrict__ h2,
                                                 const float* __restrict__ Wc,
                                                 const float* __restrict__ bc,
                                                 const float* __restrict__ W1,
                                                 const float* __restrict__ b1,
                                                 const float* __restrict__ W2,
                                                 const float* __restrict__ b2,
                                                 float* __restrict__ out,
                                                 const float* __restrict__ Aa,
                                                 const float* __restrict__ Bb,
                                                 float* __restrict__ R) {
    unsigned b = blockIdx.x, tid = threadIdx.x;
    if (b < NN / 4u) {                        // 768 main blocks, 4 nodes each
        __shared__ float aL[4][CUMC];
        __shared__ float xL[4][CUMC];
        __shared__ float hL[4][HIDC];
        int sub = tid >> 6, lane = tid & 63;
        int n = b * 4 + sub;
        int p0 = rowptr[n], p1 = rowptr[n + 1];
        int dg = p1 - p0;
        float inv = 1.0f / (float)(dg > 1 ? dg : 1);
        if (lane < CUMC) {                    // gather-aggregate
            float acc = 0.0f;
            if (lane < 9) {
                for (int p = p0; p < p1; ++p) acc += h1[srcs[p] * 9 + lane];
            } else {
                int cc = lane - 9;
                for (int p = p0; p < p1; ++p) acc += h2[srcs[p] * 27 + cc];
            }
            aL[sub][lane] = acc * inv;
        }
        __syncthreads();
        if (lane < CUMC) {
            float acc = bc[lane];
#pragma unroll
            for (int k = 0; k < CUMC; ++k) acc += aL[sub][k] * Wc[k * CUMC + lane];
            xL[sub][lane] = acc > 0.0f ? acc : 0.0f;
        }
        __syncthreads();
        {
            float acc = b1[lane];
#pragma unroll
            for (int k = 0; k < CUMC; ++k) acc += xL[sub][k] * W1[k * HIDC + lane];
            hL[sub][lane] = acc > 0.0f ? acc : 0.0f;
        }
        __syncthreads();
        if (lane < OUTC) {
            float acc = b2[lane];
#pragma unroll
            for (int k = 0; k < HIDC; ++k) acc += hL[sub][k] * W2[k * OUTC + lane];
            out[n * OUTC + lane] = acc;
        }
        return;
    }
    r_slice(SL_HEAD + (b - NN / 4u) * BUD, tid, Aa, Bb, R);
}

extern "C" void kernel_launch(void* const* d_in, const int* in_sizes, int n_in,
                              void* d_out, int out_size, void* d_ws, size_t ws_size,
                              hipStream_t stream) {
    const float* x   = (const float*)d_in[0];
    const int*   ei  = (const int*)  d_in[1];
    const float* Kv  = (const float*)d_in[2];
    const float* Ws  = (const float*)d_in[3];
    const float* bsh = (const float*)d_in[4];
    const float* Wc  = (const float*)d_in[5];
    const float* bc  = (const float*)d_in[6];
    const float* W1  = (const float*)d_in[7];
    const float* b1  = (const float*)d_in[8];
    const float* W2  = (const float*)d_in[9];
    const float* b2  = (const float*)d_in[10];

    const int* src = ei;
    const int* tgt = ei + EE;

    float* out  = (float*)d_out;                 // [N,5]
    float* Rout = out + NN * OUTC;               // [N,N,9], 16B-aligned

    // ---- workspace layout ----
    int* wsi = (int*)d_ws;
    int* cnt    = wsi;                 // 3072
    int* rowptr = cnt + NN;            // 3073
    int* cursor = rowptr + (NN + 1);   // 3072
    int* srcs   = cursor + NN;         // EE
    int* eids   = srcs + EE;           // EE
    float* wsf = (float*)(eids + EE);
    float* h1  = wsf;                  // N*9
    float* h2  = h1 + NN * 9;          // N*27
    float* Aa  = h2 + NN * 27;         // N*9  (bias folded in)
    float* Bb  = Aa + NN * 9;          // N*9

    // zero only the histogram counters
    (void)hipMemsetAsync(cnt, 0, NN * sizeof(int), stream);

    // fused A/B producer + degree histogram (no helpers — Aa/Bb not ready yet)
    abhist<<<108 + EE / 256, 256, 0, stream>>>(x, Ws, bsh, tgt, Aa, Bb, cnt);

    // chain kernels, each overlapped with a static slice of the R stream
    scan_help<<<1 + HELP_S, 1024, 0, stream>>>(cnt, rowptr, cursor, Aa, Bb, Rout);
    scatter_help<<<EE / 256 + HELP2, 256, 0, stream>>>(src, tgt, cursor, srcs, eids,
                                                       Aa, Bb, Rout);
    hop1_help<<<(NN * 9) / 256 + HELP2, 256, 0, stream>>>(rowptr, srcs, eids, Kv, x, h1,
                                                          Aa, Bb, Rout);
    hop2_help<<<(NN * 27) / 256 + HELP2, 256, 0, stream>>>(rowptr, srcs, eids, Kv, h1, h2,
                                                           Aa, Bb, Rout);
    head_help<<<NN / 4 + HELP2, 256, 0, stream>>>(rowptr, srcs, h1, h2, Wc, bc,
                                                  W1, b1, W2, b2, out, Aa, Bb, Rout);
}